// Round 4
// baseline (160.900 us; speedup 1.0000x reference)
//
#include <hip/hip_runtime.h>

#define HD 10
#define C2 20
#define PIX (192*192)
#define NB 8
#define NPIX (NB*PIX)
#define CHW (NB*HD*PIX)
#define EPSB 1e-5f
#define PXB 512              // pixels per block (256 threads x 2)
#define BPB (PIX/PXB)        // blocks per batch image = 72

__device__ __forceinline__ float sigm(float x) {
    return __builtin_amdgcn_rcpf(1.0f + __expf(-x));
}
__device__ __forceinline__ float tanh_fast(float x) {
    return 1.0f - 2.0f * __builtin_amdgcn_rcpf(1.0f + __expf(2.0f * x));
}

// Single fused kernel, 2 pixels/thread (float2), halves interleaved on grid.x.
// Weight/BN reads are wave-uniform with compile-time offsets -> scalar loads,
// each shared by the two per-thread pixel chains (ILP x2 per s_load).
__global__ __launch_bounds__(256, 3) void half_kernel(
    const float* __restrict__ xf, const float* __restrict__ xh, const float* __restrict__ xp,
    const float* __restrict__ h_att, const float* __restrict__ p_att,
    const float* __restrict__ dW1, const float* __restrict__ dbn1,
    const float* __restrict__ dW2, const float* __restrict__ dbn2,
    const float* __restrict__ uW1, const float* __restrict__ ubn1,
    const float* __restrict__ uW2, const float* __restrict__ ubn2,
    const float* __restrict__ lW1, const float* __restrict__ lbn1,
    const float* __restrict__ lW2, const float* __restrict__ lbn2,
    const float* __restrict__ guWg, const float* __restrict__ gubg,
    const float* __restrict__ guWc, const float* __restrict__ gubc,
    const float* __restrict__ glWg, const float* __restrict__ glbg,
    const float* __restrict__ glWc, const float* __restrict__ glbc,
    float* __restrict__ out)
{
    const int bid  = blockIdx.x;
    const int half = bid & 1;                    // interleaved for load balance
    const int bx   = bid >> 1;
    const int b    = bx / BPB;                   // uniform per block
    const int s    = (bx - b * BPB) * PXB + threadIdx.x * 2;
    const int base  = b * (HD*PIX) + s;          // [B,HD,P] tensors: + c*PIX
    const int abase = b * PIX + s;               // [*,B,1,P] attention maps

    // wave-uniform weight/BN pointers (selected by uniform `half`)
    const float* Wc1  = half ? lW1  : uW1;
    const float* cbn1 = half ? lbn1 : ubn1;
    const float* Wc2  = half ? lW2  : uW2;
    const float* cbn2 = half ? lbn2 : ubn2;
    const float* Wg = half ? glWg : guWg;
    const float* bg = half ? glbg : gubg;
    const float* Wc = half ? glWc : guWc;
    const float* bc = half ? glbc : gubc;

    const float* xhh = xh + half * CHW;
    float* outh = out + half * CHW;

#define LD2(p, off) (*reinterpret_cast<const float2*>((p) + (off)))

    float vxhx[HD], vxhy[HD];
    #pragma unroll
    for (int c = 0; c < HD; ++c) {
        float2 v = LD2(xhh, base + c*PIX);
        vxhx[c] = v.x; vxhy[c] = v.y;
    }

    const float2 hav = LD2(h_att, (1 + half) * NPIX + abase);
    float cax = 0.f, cay = 0.f;
    {
        const int mstart = half ? 5 : 1;
        const int natt   = half ? 2 : 4;
        for (int j = 0; j < natt; ++j) {
            float2 v = LD2(p_att, (mstart + j) * NPIX + abase);
            cax += v.x; cay += v.y;
        }
    }

    // ---- decomposition block -> message accumulator m ----
    float mx[HD], my[HD];
    {
        float inx[C2], iny[C2];
        #pragma unroll
        for (int c = 0; c < HD; ++c) {
            float2 v = LD2(xf, base + c*PIX);
            inx[c] = v.x * hav.x;  iny[c] = v.y * hav.y;
            inx[HD + c] = vxhx[c]; iny[HD + c] = vxhy[c];
        }
        float h0x[C2], h0y[C2];
        #pragma unroll
        for (int o = 0; o < C2; ++o) {
            float ax = 0.f, ay = 0.f;
            #pragma unroll
            for (int k = 0; k < C2; ++k) {
                float w = dW1[o*C2 + k];
                ax = fmaf(w, inx[k], ax);
                ay = fmaf(w, iny[k], ay);
            }
            float sc = dbn1[o] * rsqrtf(dbn1[3*C2 + o] + EPSB);
            float tr = dbn1[C2 + o] - sc * dbn1[2*C2 + o];
            h0x[o] = fmaxf(fmaf(ax, sc, tr), 0.f);
            h0y[o] = fmaxf(fmaf(ay, sc, tr), 0.f);
        }
        #pragma unroll
        for (int o = 0; o < HD; ++o) {
            float ax = 0.f, ay = 0.f;
            #pragma unroll
            for (int k = 0; k < C2; ++k) {
                float w = dW2[o*C2 + k];
                ax = fmaf(w, h0x[k], ax);
                ay = fmaf(w, h0y[k], ay);
            }
            float sc = dbn2[o] * rsqrtf(dbn2[3*HD + o] + EPSB);
            float tr = dbn2[HD + o] - sc * dbn2[2*HD + o];
            mx[o] = fmaxf(fmaf(ax, sc, tr), 0.f);
            my[o] = fmaxf(fmaf(ay, sc, tr), 0.f);
        }
    }

    // ---- composition blocks ----
    {
        float s1[C2], s2[HD], t2[HD];           // uniform BN constants (reused)
        #pragma unroll
        for (int o = 0; o < C2; ++o)
            s1[o] = cbn1[o] * rsqrtf(cbn1[3*C2 + o] + EPSB);
        #pragma unroll
        for (int o = 0; o < HD; ++o) {
            s2[o] = cbn2[o] * rsqrtf(cbn2[3*HD + o] + EPSB);
            t2[o] = cbn2[HD + o] - s2[o] * cbn2[2*HD + o];
        }
        // pre[] = BN-affine of the shared xh-half of conv1 (t1 folded in)
        float prex[C2], prey[C2];
        #pragma unroll
        for (int o = 0; o < C2; ++o) {
            float ax = 0.f, ay = 0.f;
            #pragma unroll
            for (int k = 0; k < HD; ++k) {
                float w = Wc1[o*C2 + k];
                ax = fmaf(w, vxhx[k], ax);
                ay = fmaf(w, vxhy[k], ay);
            }
            float t1 = cbn1[C2 + o] - s1[o] * cbn1[2*C2 + o];
            prex[o] = fmaf(ax, s1[o], t1);
            prey[o] = fmaf(ay, s1[o], t1);
        }
        const int pstart = half ? 4 : 0;
        const int nparts = half ? 2 : 4;
        for (int i = 0; i < nparts; ++i) {      // runtime loop: bounds live range
            float xpx[HD], xpy[HD];
            #pragma unroll
            for (int c = 0; c < HD; ++c) {
                float2 v = LD2(xp, (pstart + i) * CHW + base + c*PIX);
                xpx[c] = v.x * cax; xpy[c] = v.y * cay;
            }
            float hx[C2], hy[C2];
            #pragma unroll
            for (int o = 0; o < C2; ++o) {
                float ax = 0.f, ay = 0.f;
                #pragma unroll
                for (int k = 0; k < HD; ++k) {
                    float w = Wc1[o*C2 + HD + k];
                    ax = fmaf(w, xpx[k], ax);
                    ay = fmaf(w, xpy[k], ay);
                }
                hx[o] = fmaxf(fmaf(ax, s1[o], prex[o]), 0.f);
                hy[o] = fmaxf(fmaf(ay, s1[o], prey[o]), 0.f);
            }
            #pragma unroll
            for (int o = 0; o < HD; ++o) {
                float ax = 0.f, ay = 0.f;
                #pragma unroll
                for (int k = 0; k < C2; ++k) {
                    float w = Wc2[o*C2 + k];
                    ax = fmaf(w, hx[k], ax);
                    ay = fmaf(w, hy[k], ay);
                }
                mx[o] += fmaxf(fmaf(ax, s2[o], t2[o]), 0.f);
                my[o] += fmaxf(fmaf(ay, s2[o], t2[o]), 0.f);
            }
        }
    }

    // ---- GRU ----
    float gx[C2], gy[C2];
    #pragma unroll
    for (int o = 0; o < C2; ++o) {
        float ax = bg[o], ay = ax;
        #pragma unroll
        for (int k = 0; k < HD; ++k) {
            float w = Wg[o*C2 + k];
            ax = fmaf(w, mx[k], ax);
            ay = fmaf(w, my[k], ay);
        }
        #pragma unroll
        for (int k = 0; k < HD; ++k) {
            float w = Wg[o*C2 + HD + k];
            ax = fmaf(w, vxhx[k], ax);
            ay = fmaf(w, vxhy[k], ay);
        }
        gx[o] = sigm(ax);
        gy[o] = sigm(ay);
    }
    float rhx[HD], rhy[HD];
    #pragma unroll
    for (int k = 0; k < HD; ++k) {
        rhx[k] = gx[k] * vxhx[k];
        rhy[k] = gy[k] * vxhy[k];
    }
    #pragma unroll
    for (int o = 0; o < HD; ++o) {
        float ax = bc[o], ay = ax;
        #pragma unroll
        for (int k = 0; k < HD; ++k) {
            float w = Wc[o*C2 + k];
            ax = fmaf(w, mx[k], ax);
            ay = fmaf(w, my[k], ay);
        }
        #pragma unroll
        for (int k = 0; k < HD; ++k) {
            float w = Wc[o*C2 + HD + k];
            ax = fmaf(w, rhx[k], ax);
            ay = fmaf(w, rhy[k], ay);
        }
        float cxv = tanh_fast(ax), cyv = tanh_fast(ay);
        float2 o2;
        o2.x = fmaf(gx[HD + o], cxv - vxhx[o], vxhx[o]);   // (1-u)*h + u*c
        o2.y = fmaf(gy[HD + o], cyv - vxhy[o], vxhy[o]);
        *reinterpret_cast<float2*>(outh + base + o*PIX) = o2;
    }
#undef LD2
}

extern "C" void kernel_launch(void* const* d_in, const int* in_sizes, int n_in,
                              void* d_out, int out_size, void* d_ws, size_t ws_size,
                              hipStream_t stream) {
    const float* xf    = (const float*)d_in[0];
    const float* xh    = (const float*)d_in[1];
    const float* xp    = (const float*)d_in[2];
    const float* h_att = (const float*)d_in[3];
    const float* p_att = (const float*)d_in[4];
    const float* dW1   = (const float*)d_in[5];
    const float* dbn1  = (const float*)d_in[6];
    const float* dW2   = (const float*)d_in[7];
    const float* dbn2  = (const float*)d_in[8];
    const float* uW1   = (const float*)d_in[9];
    const float* ubn1  = (const float*)d_in[10];
    const float* uW2   = (const float*)d_in[11];
    const float* ubn2  = (const float*)d_in[12];
    const float* lW1   = (const float*)d_in[13];
    const float* lbn1  = (const float*)d_in[14];
    const float* lW2   = (const float*)d_in[15];
    const float* lbn2  = (const float*)d_in[16];
    const float* guWg  = (const float*)d_in[17];
    const float* gubg  = (const float*)d_in[18];
    const float* guWc  = (const float*)d_in[19];
    const float* gubc  = (const float*)d_in[20];
    const float* glWg  = (const float*)d_in[21];
    const float* glbg  = (const float*)d_in[22];
    const float* glWc  = (const float*)d_in[23];
    const float* glbc  = (const float*)d_in[24];

    dim3 grid((NPIX / PXB) * 2), block(256);
    half_kernel<<<grid, block, 0, stream>>>(
        xf, xh, xp, h_att, p_att,
        dW1, dbn1, dW2, dbn2,
        uW1, ubn1, uW2, ubn2,
        lW1, lbn1, lW2, lbn2,
        guWg, gubg, guWc, gubc,
        glWg, glbg, glWc, glbc,
        (float*)d_out);
}

// Round 5
// 94.385 us; speedup vs baseline: 1.7047x; 1.7047x over previous
//
#include <hip/hip_runtime.h>

#define HD 10
#define C2 20
#define PIX (192*192)
#define NB 8
#define NPIX (NB*PIX)
#define CHW (NB*HD*PIX)
#define EPSB 1e-5f
#define BPB (PIX/256)        // blocks per (batch,half) image = 144

__device__ __forceinline__ float sigm(float x) {
    return __builtin_amdgcn_rcpf(1.0f + __expf(-x));
}
__device__ __forceinline__ float tanh_fast(float x) {
    return 1.0f - 2.0f * __builtin_amdgcn_rcpf(1.0f + __expf(2.0f * x));
}

// Single fused kernel, 1 pixel/thread, halves interleaved on grid.x.
// Weight/BN reads are wave-uniform with compile-time offsets -> scalar loads.
// Comp part-loop statically unrolled (uniform-guarded) so weight streams hoist
// and xp loads pipeline across parts.
__global__ __launch_bounds__(256) void half_kernel(
    const float* __restrict__ xf, const float* __restrict__ xh, const float* __restrict__ xp,
    const float* __restrict__ h_att, const float* __restrict__ p_att,
    const float* __restrict__ dW1, const float* __restrict__ dbn1,
    const float* __restrict__ dW2, const float* __restrict__ dbn2,
    const float* __restrict__ uW1, const float* __restrict__ ubn1,
    const float* __restrict__ uW2, const float* __restrict__ ubn2,
    const float* __restrict__ lW1, const float* __restrict__ lbn1,
    const float* __restrict__ lW2, const float* __restrict__ lbn2,
    const float* __restrict__ guWg, const float* __restrict__ gubg,
    const float* __restrict__ guWc, const float* __restrict__ gubc,
    const float* __restrict__ glWg, const float* __restrict__ glbg,
    const float* __restrict__ glWc, const float* __restrict__ glbc,
    float* __restrict__ out)
{
    const int bid  = blockIdx.x;
    const int half = bid & 1;                    // interleaved for load balance
    const int bx   = bid >> 1;
    const int b    = bx / BPB;                   // uniform per block
    const int s    = (bx - b * BPB) * 256 + threadIdx.x;
    const int base  = b * (HD*PIX) + s;          // [B,HD,P] tensors: + c*PIX
    const int abase = b * PIX + s;               // [*,B,1,P] attention maps

    // wave-uniform weight/BN pointers (selected by uniform `half`)
    const float* Wc1  = half ? lW1  : uW1;
    const float* cbn1 = half ? lbn1 : ubn1;
    const float* Wc2  = half ? lW2  : uW2;
    const float* cbn2 = half ? lbn2 : ubn2;
    const float* Wg = half ? glWg : guWg;
    const float* bg = half ? glbg : gubg;
    const float* Wc = half ? glWc : guWc;
    const float* bc = half ? glbc : gubc;

    const float* xhh = xh + half * CHW;
    float* outh = out + half * CHW;

    float vxh[HD];
    #pragma unroll
    for (int c = 0; c < HD; ++c) vxh[c] = xhh[base + c*PIX];

    const float ha = h_att[(1 + half) * NPIX + abase];
    float catt = 0.f;
    {
        const int mstart = half ? 5 : 1;
        const int natt   = half ? 2 : 4;
        #pragma unroll
        for (int j = 0; j < 4; ++j)
            if (j < natt) catt += p_att[(mstart + j) * NPIX + abase];
    }

    // ---- decomposition block -> message accumulator m (BN applied inline) ----
    float m[HD];
    {
        float in[C2];
        #pragma unroll
        for (int c = 0; c < HD; ++c) { in[c] = xf[base + c*PIX] * ha; in[HD + c] = vxh[c]; }
        float h[C2];
        #pragma unroll
        for (int o = 0; o < C2; ++o) {
            float a = 0.f;
            #pragma unroll
            for (int k = 0; k < C2; ++k) a = fmaf(dW1[o*C2 + k], in[k], a);
            float sc = dbn1[o] * rsqrtf(dbn1[3*C2 + o] + EPSB);
            float tr = dbn1[C2 + o] - sc * dbn1[2*C2 + o];
            h[o] = fmaxf(fmaf(a, sc, tr), 0.f);
        }
        #pragma unroll
        for (int o = 0; o < HD; ++o) {
            float a = 0.f;
            #pragma unroll
            for (int k = 0; k < C2; ++k) a = fmaf(dW2[o*C2 + k], h[k], a);
            float sc = dbn2[o] * rsqrtf(dbn2[3*HD + o] + EPSB);
            float tr = dbn2[HD + o] - sc * dbn2[2*HD + o];
            m[o] = fmaxf(fmaf(a, sc, tr), 0.f);
        }
    }

    // ---- composition blocks (part loop statically unrolled, uniform guards) ----
    {
        float s1[C2], s2[HD], t2[HD];            // uniform BN constants (reused)
        #pragma unroll
        for (int o = 0; o < C2; ++o)
            s1[o] = cbn1[o] * rsqrtf(cbn1[3*C2 + o] + EPSB);
        #pragma unroll
        for (int o = 0; o < HD; ++o) {
            s2[o] = cbn2[o] * rsqrtf(cbn2[3*HD + o] + EPSB);
            t2[o] = cbn2[HD + o] - s2[o] * cbn2[2*HD + o];
        }
        // pre[] = BN-affine of the shared xh-half of conv1 (t1 folded in)
        float pre[C2];
        #pragma unroll
        for (int o = 0; o < C2; ++o) {
            float a = 0.f;
            #pragma unroll
            for (int k = 0; k < HD; ++k) a = fmaf(Wc1[o*C2 + k], vxh[k], a);
            float t1 = cbn1[C2 + o] - s1[o] * cbn1[2*C2 + o];
            pre[o] = fmaf(a, s1[o], t1);
        }
        const int pstart = half ? 4 : 0;
        const int nparts = half ? 2 : 4;
        #pragma unroll
        for (int i = 0; i < 4; ++i) {
            if (i < nparts) {                    // wave-uniform guard
                float xpi[HD];
                #pragma unroll
                for (int c = 0; c < HD; ++c)
                    xpi[c] = xp[(pstart + i) * CHW + base + c*PIX] * catt;
                float h[C2];
                #pragma unroll
                for (int o = 0; o < C2; ++o) {
                    float a = 0.f;
                    #pragma unroll
                    for (int k = 0; k < HD; ++k) a = fmaf(Wc1[o*C2 + HD + k], xpi[k], a);
                    h[o] = fmaxf(fmaf(a, s1[o], pre[o]), 0.f);
                }
                #pragma unroll
                for (int o = 0; o < HD; ++o) {
                    float a = 0.f;
                    #pragma unroll
                    for (int k = 0; k < C2; ++k) a = fmaf(Wc2[o*C2 + k], h[k], a);
                    m[o] += fmaxf(fmaf(a, s2[o], t2[o]), 0.f);
                }
            }
        }
    }

    // ---- GRU ----
    float g[C2];
    #pragma unroll
    for (int o = 0; o < C2; ++o) {
        float a = bg[o];
        #pragma unroll
        for (int k = 0; k < HD; ++k) a = fmaf(Wg[o*C2 + k], m[k], a);
        #pragma unroll
        for (int k = 0; k < HD; ++k) a = fmaf(Wg[o*C2 + HD + k], vxh[k], a);
        g[o] = sigm(a);
    }
    float rh[HD];
    #pragma unroll
    for (int k = 0; k < HD; ++k) rh[k] = g[k] * vxh[k];
    #pragma unroll
    for (int o = 0; o < HD; ++o) {
        float a = bc[o];
        #pragma unroll
        for (int k = 0; k < HD; ++k) a = fmaf(Wc[o*C2 + k], m[k], a);
        #pragma unroll
        for (int k = 0; k < HD; ++k) a = fmaf(Wc[o*C2 + HD + k], rh[k], a);
        float c = tanh_fast(a);
        float u = g[HD + o];
        outh[base + o*PIX] = fmaf(u, c - vxh[o], vxh[o]);   // (1-u)*h + u*c
    }
}

extern "C" void kernel_launch(void* const* d_in, const int* in_sizes, int n_in,
                              void* d_out, int out_size, void* d_ws, size_t ws_size,
                              hipStream_t stream) {
    const float* xf    = (const float*)d_in[0];
    const float* xh    = (const float*)d_in[1];
    const float* xp    = (const float*)d_in[2];
    const float* h_att = (const float*)d_in[3];
    const float* p_att = (const float*)d_in[4];
    const float* dW1   = (const float*)d_in[5];
    const float* dbn1  = (const float*)d_in[6];
    const float* dW2   = (const float*)d_in[7];
    const float* dbn2  = (const float*)d_in[8];
    const float* uW1   = (const float*)d_in[9];
    const float* ubn1  = (const float*)d_in[10];
    const float* uW2   = (const float*)d_in[11];
    const float* ubn2  = (const float*)d_in[12];
    const float* lW1   = (const float*)d_in[13];
    const float* lbn1  = (const float*)d_in[14];
    const float* lW2   = (const float*)d_in[15];
    const float* lbn2  = (const float*)d_in[16];
    const float* guWg  = (const float*)d_in[17];
    const float* gubg  = (const float*)d_in[18];
    const float* guWc  = (const float*)d_in[19];
    const float* gubc  = (const float*)d_in[20];
    const float* glWg  = (const float*)d_in[21];
    const float* glbg  = (const float*)d_in[22];
    const float* glWc  = (const float*)d_in[23];
    const float* glbc  = (const float*)d_in[24];

    dim3 grid((NPIX / 256) * 2), block(256);
    half_kernel<<<grid, block, 0, stream>>>(
        xf, xh, xp, h_att, p_att,
        dW1, dbn1, dW2, dbn2,
        uW1, ubn1, uW2, ubn2,
        lW1, lbn1, lW2, lbn2,
        guWg, gubg, guWc, gubc,
        glWg, glbg, glWc, glbc,
        (float*)d_out);
}